// Round 1
// baseline (359.811 us; speedup 1.0000x reference)
//
#include <hip/hip_runtime.h>
#include <math.h>

#define TB 2
#define TT 2048
#define TC 1024
#define TH 16
#define THD 64
#define TM (TB*TT)   // 4096 tokens

typedef __bf16 bf16x8 __attribute__((ext_vector_type(8)));
typedef float f32x4 __attribute__((ext_vector_type(4)));
typedef unsigned short u16x8 __attribute__((ext_vector_type(8)));
typedef unsigned short u16x4 __attribute__((ext_vector_type(4)));

__device__ __forceinline__ unsigned short f2bf(float f){
    unsigned int u = __builtin_bit_cast(unsigned int, f);
    u = (u + 0x7FFFu + ((u >> 16) & 1u)) >> 16;
    return (unsigned short)u;
}
__device__ __forceinline__ float bf2f(unsigned short h){
    unsigned int u = ((unsigned int)h) << 16;
    return __builtin_bit_cast(float, u);
}
__device__ __forceinline__ bf16x8 ldbf8(const unsigned short* p){
    return __builtin_bit_cast(bf16x8, *(const u16x8*)p);
}
__device__ __forceinline__ void gl_lds16(const void* g, void* l){
    __builtin_amdgcn_global_load_lds(
        (const __attribute__((address_space(1))) unsigned int*)g,
        (__attribute__((address_space(3))) unsigned int*)l,
        16, 0, 0);
}
__device__ __forceinline__ float gelu_tanh(float v){
    float u = 2.0f * 0.7978845608028654f * (v + 0.044715f * v * v * v);
    u = fminf(fmaxf(u, -30.f), 30.f);
    float e = __expf(u);
    return 0.5f * v * (1.f + (e - 1.f) / (e + 1.f));
}

// ---------------- weight convert+transpose: in [K][N] f32 -> out [N][K] bf16
__global__ __launch_bounds__(256)
void convert_transpose(const float* __restrict__ in, unsigned short* __restrict__ out,
                       int K, int N){
    __shared__ float tile[32][33];
    int tx = threadIdx.x, ty = threadIdx.y;
    int n0 = blockIdx.x * 32, k0 = blockIdx.y * 32;
    #pragma unroll
    for (int i = 0; i < 4; i++)
        tile[ty + 8*i][tx] = in[(size_t)(k0 + ty + 8*i) * N + n0 + tx];
    __syncthreads();
    #pragma unroll
    for (int i = 0; i < 4; i++)
        out[(size_t)(n0 + ty + 8*i) * K + k0 + tx] = f2bf(tile[tx][ty + 8*i]);
}

// ---------------- layernorm: x f32 [.][1024] -> y bf16
__global__ __launch_bounds__(256)
void ln_kernel(const float* __restrict__ x, const float* __restrict__ g,
               const float* __restrict__ be, unsigned short* __restrict__ y){
    const int row = blockIdx.x, t = threadIdx.x;
    const float4* xr = (const float4*)(x + (size_t)row * TC);
    float4 v = xr[t];
    float s  = v.x + v.y + v.z + v.w;
    float s2 = v.x*v.x + v.y*v.y + v.z*v.z + v.w*v.w;
    #pragma unroll
    for (int off = 32; off; off >>= 1){
        s  += __shfl_down(s,  off);
        s2 += __shfl_down(s2, off);
    }
    __shared__ float red[8];
    int l = t & 63, wv = t >> 6;
    if (l == 0){ red[wv] = s; red[4 + wv] = s2; }
    __syncthreads();
    float S  = red[0] + red[1] + red[2] + red[3];
    float S2 = red[4] + red[5] + red[6] + red[7];
    float mu = S * (1.f / TC);
    float var = S2 * (1.f / TC) - mu * mu;
    float rs = rsqrtf(var + 1e-5f);
    int c = t * 4;
    float4 gg = *(const float4*)(g + c);
    float4 bb = *(const float4*)(be + c);
    u16x4 o;
    o[0] = f2bf((v.x - mu) * rs * gg.x + bb.x);
    o[1] = f2bf((v.y - mu) * rs * gg.y + bb.y);
    o[2] = f2bf((v.z - mu) * rs * gg.z + bb.z);
    o[3] = f2bf((v.w - mu) * rs * gg.w + bb.w);
    *(u16x4*)(y + (size_t)row * TC + c) = o;
}

// ---------------- GEMM: A [M][K] bf16, Bt [N][K] bf16 -> out [M][N]
// EPI 0: +bias -> bf16 ; 1: +bias+resid -> f32 ; 2: +bias, gelu -> bf16
template<int EPI>
__global__ __launch_bounds__(256, 2)
void gemm_bt(const unsigned short* __restrict__ A,
             const unsigned short* __restrict__ Bt,
             const float* __restrict__ bias,
             const float* __restrict__ resid,
             void* __restrict__ outv,
             int M, int N, int K){
    __shared__ unsigned short lA[128 * 32];
    __shared__ unsigned short lB[128 * 32];
    const int t = threadIdx.x, w = t >> 6, l = t & 63, lr = l & 15, lg = l >> 4;
    const int nt = N >> 7;
    const int bm = blockIdx.x / nt, bn = blockIdx.x % nt;
    const int row0 = bm << 7, col0 = bn << 7;
    const int wr = w >> 1, wc = w & 1;

    f32x4 acc[4][4];
    #pragma unroll
    for (int i = 0; i < 4; i++)
        #pragma unroll
        for (int j = 0; j < 4; j++) acc[i][j] = (f32x4){0.f,0.f,0.f,0.f};

    const char* Ag = (const char*)(A + (size_t)(row0 + (t >> 2)) * K) + (t & 3) * 16;
    const char* Bg = (const char*)(Bt + (size_t)(col0 + (t >> 2)) * K) + (t & 3) * 16;
    const size_t rstep = (size_t)64 * K * 2;
    char* lAw = (char*)lA + w * 1024;
    char* lBw = (char*)lB + w * 1024;

    for (int k0 = 0; k0 < K; k0 += 32){
        size_t kb = (size_t)k0 * 2;
        gl_lds16(Ag + kb,          lAw);
        gl_lds16(Ag + kb + rstep,  lAw + 4096);
        gl_lds16(Bg + kb,          lBw);
        gl_lds16(Bg + kb + rstep,  lBw + 4096);
        __syncthreads();
        bf16x8 af[4], bfr[4];
        #pragma unroll
        for (int mi = 0; mi < 4; mi++)
            af[mi] = ldbf8(lA + (wr*64 + mi*16 + lr) * 32 + lg * 8);
        #pragma unroll
        for (int ni = 0; ni < 4; ni++)
            bfr[ni] = ldbf8(lB + (wc*64 + ni*16 + lr) * 32 + lg * 8);
        #pragma unroll
        for (int mi = 0; mi < 4; mi++)
            #pragma unroll
            for (int ni = 0; ni < 4; ni++)
                acc[mi][ni] = __builtin_amdgcn_mfma_f32_16x16x32_bf16(
                    af[mi], bfr[ni], acc[mi][ni], 0, 0, 0);
        __syncthreads();
    }

    float bcol[4];
    #pragma unroll
    for (int ni = 0; ni < 4; ni++) bcol[ni] = bias[col0 + wc*64 + ni*16 + lr];
    #pragma unroll
    for (int mi = 0; mi < 4; mi++){
        #pragma unroll
        for (int j = 0; j < 4; j++){
            int row = row0 + wr*64 + mi*16 + lg*4 + j;
            size_t base = (size_t)row * N + col0 + wc*64 + lr;
            #pragma unroll
            for (int ni = 0; ni < 4; ni++){
                float v = acc[mi][ni][j] + bcol[ni];
                size_t idx = base + (size_t)ni * 16;
                if (EPI == 0)      ((unsigned short*)outv)[idx] = f2bf(v);
                else if (EPI == 1) ((float*)outv)[idx] = v + resid[idx];
                else               ((unsigned short*)outv)[idx] = f2bf(gelu_tanh(v));
            }
        }
    }
}

// ---------------- flash attention (causal), qkv bf16 [M][3C] -> attn_out bf16 [M][C]
__global__ __launch_bounds__(256, 2)
void attn_kernel(const unsigned short* __restrict__ qkv,
                 unsigned short* __restrict__ attn_out){
    constexpr int NQ = TT / 64;
    int bid = blockIdx.x;
    int qt = bid % NQ;
    int bh = bid / NQ;
    int h = bh % TH, b = bh / TH;
    int t = threadIdx.x, w = t >> 6, l = t & 63, lr = l & 15, lg = l >> 4;

    __shared__ unsigned short vT[64][80];      // V^T: [d][kv], stride 160B
    __shared__ unsigned short pl[4][16][80];   // per-wave P tiles

    const unsigned short* qb =
        qkv + (size_t)(b*TT + qt*64 + w*16 + lr) * (3*TC) + h*THD;
    bf16x8 qf0 = ldbf8(qb + lg*8);
    bf16x8 qf1 = ldbf8(qb + 32 + lg*8);

    f32x4 o[4];
    float m[4], ls[4];
    #pragma unroll
    for (int db = 0; db < 4; db++) o[db] = (f32x4){0.f,0.f,0.f,0.f};
    #pragma unroll
    for (int j = 0; j < 4; j++){ m[j] = -1e30f; ls[j] = 0.f; }

    for (int kt = 0; kt <= qt; ++kt){
        // V tile -> registers
        int kvr = kt*64 + (t >> 2);
        const unsigned short* vb =
            qkv + (size_t)(b*TT + kvr) * (3*TC) + 2*TC + h*THD + (t & 3) * 8;
        u16x8 v0 = *(const u16x8*)vb;
        u16x8 v1 = *(const u16x8*)(vb + 32);
        __syncthreads();   // prior iteration's vT reads done
        {
            int d0 = (t & 3) * 8, kvl = t >> 2;
            #pragma unroll
            for (int j2 = 0; j2 < 8; j2++){
                vT[d0 + j2][kvl]      = v0[j2];
                vT[32 + d0 + j2][kvl] = v1[j2];
            }
        }
        // S = Q K^T
        f32x4 s[4];
        #pragma unroll
        for (int cb = 0; cb < 4; cb++){
            const unsigned short* kb =
                qkv + (size_t)(b*TT + kt*64 + cb*16 + lr) * (3*TC) + TC + h*THD;
            bf16x8 kf0 = ldbf8(kb + lg*8);
            bf16x8 kf1 = ldbf8(kb + 32 + lg*8);
            f32x4 z = (f32x4){0.f,0.f,0.f,0.f};
            z = __builtin_amdgcn_mfma_f32_16x16x32_bf16(qf0, kf0, z, 0,0,0);
            z = __builtin_amdgcn_mfma_f32_16x16x32_bf16(qf1, kf1, z, 0,0,0);
            s[cb] = z;
        }
        bool diag = (kt == qt);
        #pragma unroll
        for (int cb = 0; cb < 4; cb++)
            #pragma unroll
            for (int j = 0; j < 4; j++){
                float v = s[cb][j] * 0.125f;
                if (diag){
                    int qg = qt*64 + w*16 + lg*4 + j;
                    int kv = kt*64 + cb*16 + lr;
                    if (kv > qg) v = -1e30f;
                }
                s[cb][j] = v;
            }
        // online softmax
        float mloc[4], al[4], ps[4];
        #pragma unroll
        for (int j = 0; j < 4; j++)
            mloc[j] = fmaxf(fmaxf(s[0][j], s[1][j]), fmaxf(s[2][j], s[3][j]));
        #pragma unroll
        for (int off = 1; off < 16; off <<= 1)
            #pragma unroll
            for (int j = 0; j < 4; j++)
                mloc[j] = fmaxf(mloc[j], __shfl_xor(mloc[j], off));
        #pragma unroll
        for (int j = 0; j < 4; j++){
            float mn = fmaxf(m[j], mloc[j]);
            al[j] = __expf(m[j] - mn);
            m[j] = mn;
        }
        #pragma unroll
        for (int cb = 0; cb < 4; cb++)
            #pragma unroll
            for (int j = 0; j < 4; j++)
                s[cb][j] = __expf(s[cb][j] - m[j]);
        #pragma unroll
        for (int j = 0; j < 4; j++){
            ps[j] = s[0][j] + s[1][j] + s[2][j] + s[3][j];
        }
        #pragma unroll
        for (int off = 1; off < 16; off <<= 1)
            #pragma unroll
            for (int j = 0; j < 4; j++)
                ps[j] += __shfl_xor(ps[j], off);
        #pragma unroll
        for (int j = 0; j < 4; j++) ls[j] = ls[j] * al[j] + ps[j];
        #pragma unroll
        for (int db = 0; db < 4; db++)
            #pragma unroll
            for (int j = 0; j < 4; j++) o[db][j] *= al[j];
        // P -> LDS (bf16)
        #pragma unroll
        for (int cb = 0; cb < 4; cb++)
            #pragma unroll
            for (int j = 0; j < 4; j++)
                pl[w][lg*4 + j][cb*16 + lr] = f2bf(s[cb][j]);
        __syncthreads();   // vT visible to all waves
        // O += P V
        bf16x8 pa0 = ldbf8(&pl[w][lr][lg*8]);
        bf16x8 pa1 = ldbf8(&pl[w][lr][32 + lg*8]);
        #pragma unroll
        for (int db = 0; db < 4; db++){
            bf16x8 vf0 = ldbf8(&vT[db*16 + lr][lg*8]);
            bf16x8 vf1 = ldbf8(&vT[db*16 + lr][32 + lg*8]);
            o[db] = __builtin_amdgcn_mfma_f32_16x16x32_bf16(pa0, vf0, o[db], 0,0,0);
            o[db] = __builtin_amdgcn_mfma_f32_16x16x32_bf16(pa1, vf1, o[db], 0,0,0);
        }
    }
    #pragma unroll
    for (int db = 0; db < 4; db++)
        #pragma unroll
        for (int j = 0; j < 4; j++){
            size_t tok = (size_t)(b*TT + qt*64 + w*16 + lg*4 + j);
            attn_out[tok * TC + h*THD + db*16 + lr] = f2bf(o[db][j] / ls[j]);
        }
}

extern "C" void kernel_launch(void* const* d_in, const int* in_sizes, int n_in,
                              void* d_out, int out_size, void* d_ws, size_t ws_size,
                              hipStream_t stream){
    const float* x      = (const float*)d_in[0];
    const float* ln1_g  = (const float*)d_in[1];
    const float* ln1_b  = (const float*)d_in[2];
    const float* w_attn = (const float*)d_in[3];
    const float* b_attn = (const float*)d_in[4];
    const float* w_proj = (const float*)d_in[5];
    const float* b_proj = (const float*)d_in[6];
    const float* ln2_g  = (const float*)d_in[7];
    const float* ln2_b  = (const float*)d_in[8];
    const float* w_fc   = (const float*)d_in[9];
    const float* b_fc   = (const float*)d_in[10];
    const float* w_fc2  = (const float*)d_in[11];
    const float* b_fc2  = (const float*)d_in[12];
    float* out = (float*)d_out;

    char* ws = (char*)d_ws;
    size_t off = 0;
    auto alloc = [&](size_t bytes) -> void* {
        void* p = ws + off;
        off += (bytes + 255) & ~(size_t)255;
        return p;
    };
    unsigned short* wattnT = (unsigned short*)alloc((size_t)3072*1024*2);
    unsigned short* wprojT = (unsigned short*)alloc((size_t)1024*1024*2);
    unsigned short* wfcT   = (unsigned short*)alloc((size_t)4096*1024*2);
    unsigned short* wfc2T  = (unsigned short*)alloc((size_t)1024*4096*2);
    unsigned short* xn1    = (unsigned short*)alloc((size_t)TM*TC*2);
    unsigned short* qkvb   = (unsigned short*)alloc((size_t)TM*3*TC*2);
    unsigned short* attnO  = (unsigned short*)alloc((size_t)TM*TC*2);
    float*          resid1 = (float*)alloc((size_t)TM*TC*4);
    unsigned short* xn2    = (unsigned short*)alloc((size_t)TM*TC*2);
    unsigned short* hbuf   = (unsigned short*)alloc((size_t)TM*4*TC*2);

    dim3 tb(32, 8, 1);
    convert_transpose<<<dim3(3072/32, 1024/32), tb, 0, stream>>>(w_attn, wattnT, 1024, 3072);
    convert_transpose<<<dim3(1024/32, 1024/32), tb, 0, stream>>>(w_proj, wprojT, 1024, 1024);
    convert_transpose<<<dim3(4096/32, 1024/32), tb, 0, stream>>>(w_fc,   wfcT,   1024, 4096);
    convert_transpose<<<dim3(1024/32, 4096/32), tb, 0, stream>>>(w_fc2,  wfc2T,  4096, 1024);

    ln_kernel<<<TM, 256, 0, stream>>>(x, ln1_g, ln1_b, xn1);

    gemm_bt<0><<<(TM/128)*(3072/128), 256, 0, stream>>>(
        xn1, wattnT, b_attn, nullptr, qkvb, TM, 3072, 1024);

    attn_kernel<<<TB*TH*(TT/64), 256, 0, stream>>>(qkvb, attnO);

    gemm_bt<1><<<(TM/128)*(1024/128), 256, 0, stream>>>(
        attnO, wprojT, b_proj, x, resid1, TM, 1024, 1024);

    ln_kernel<<<TM, 256, 0, stream>>>(resid1, ln2_g, ln2_b, xn2);

    gemm_bt<2><<<(TM/128)*(4096/128), 256, 0, stream>>>(
        xn2, wfcT, b_fc, nullptr, hbuf, TM, 4096, 1024);

    gemm_bt<1><<<(TM/128)*(1024/128), 256, 0, stream>>>(
        hbuf, wfc2T, b_fc2, resid1, out, TM, 1024, 4096);
}

// Round 2
// 332.598 us; speedup vs baseline: 1.0818x; 1.0818x over previous
//
#include <hip/hip_runtime.h>
#include <math.h>

#define TB 2
#define TT 2048
#define TC 1024
#define TH 16
#define THD 64
#define TM (TB*TT)   // 4096 tokens
#define NQT 32       // TT/64 kv/q tiles

typedef __bf16 bf16x8 __attribute__((ext_vector_type(8)));
typedef float f32x4 __attribute__((ext_vector_type(4)));
typedef unsigned short u16x8 __attribute__((ext_vector_type(8)));
typedef unsigned short u16x4 __attribute__((ext_vector_type(4)));

__device__ __forceinline__ unsigned short f2bf(float f){
    unsigned int u = __builtin_bit_cast(unsigned int, f);
    u = (u + 0x7FFFu + ((u >> 16) & 1u)) >> 16;
    return (unsigned short)u;
}
__device__ __forceinline__ bf16x8 ldbf8(const unsigned short* p){
    return __builtin_bit_cast(bf16x8, *(const u16x8*)p);
}
__device__ __forceinline__ void gl_lds16(const void* g, void* l){
    __builtin_amdgcn_global_load_lds(
        (const __attribute__((address_space(1))) unsigned int*)g,
        (__attribute__((address_space(3))) unsigned int*)l,
        16, 0, 0);
}
__device__ __forceinline__ float gelu_tanh(float v){
    float u = 2.0f * 0.7978845608028654f * (v + 0.044715f * v * v * v);
    u = fminf(fmaxf(u, -30.f), 30.f);
    float e = __expf(u);
    return 0.5f * v * (1.f + (e - 1.f) / (e + 1.f));
}

// ---------------- weight convert+transpose: in [K][N] f32 -> out [N][K] bf16
__global__ __launch_bounds__(256)
void convert_transpose(const float* __restrict__ in, unsigned short* __restrict__ out,
                       int K, int N){
    __shared__ float tile[32][33];
    int tx = threadIdx.x, ty = threadIdx.y;
    int n0 = blockIdx.x * 32, k0 = blockIdx.y * 32;
    #pragma unroll
    for (int i = 0; i < 4; i++)
        tile[ty + 8*i][tx] = in[(size_t)(k0 + ty + 8*i) * N + n0 + tx];
    __syncthreads();
    #pragma unroll
    for (int i = 0; i < 4; i++)
        out[(size_t)(n0 + ty + 8*i) * K + k0 + tx] = f2bf(tile[tx][ty + 8*i]);
}

// ---------------- layernorm: x f32 [.][1024] -> y bf16
__global__ __launch_bounds__(256)
void ln_kernel(const float* __restrict__ x, const float* __restrict__ g,
               const float* __restrict__ be, unsigned short* __restrict__ y){
    const int row = blockIdx.x, t = threadIdx.x;
    const float4* xr = (const float4*)(x + (size_t)row * TC);
    float4 v = xr[t];
    float s  = v.x + v.y + v.z + v.w;
    float s2 = v.x*v.x + v.y*v.y + v.z*v.z + v.w*v.w;
    #pragma unroll
    for (int off = 32; off; off >>= 1){
        s  += __shfl_down(s,  off);
        s2 += __shfl_down(s2, off);
    }
    __shared__ float red[8];
    int l = t & 63, wv = t >> 6;
    if (l == 0){ red[wv] = s; red[4 + wv] = s2; }
    __syncthreads();
    float S  = red[0] + red[1] + red[2] + red[3];
    float S2 = red[4] + red[5] + red[6] + red[7];
    float mu = S * (1.f / TC);
    float var = S2 * (1.f / TC) - mu * mu;
    float rs = rsqrtf(var + 1e-5f);
    int c = t * 4;
    float4 gg = *(const float4*)(g + c);
    float4 bb = *(const float4*)(be + c);
    u16x4 o;
    o[0] = f2bf((v.x - mu) * rs * gg.x + bb.x);
    o[1] = f2bf((v.y - mu) * rs * gg.y + bb.y);
    o[2] = f2bf((v.z - mu) * rs * gg.z + bb.z);
    o[3] = f2bf((v.w - mu) * rs * gg.w + bb.w);
    *(u16x4*)(y + (size_t)row * TC + c) = o;
}

// ---------------- GEMM: A [M][K] bf16, Bt [N][K] bf16 -> out [M][N]
// EPI 0: +bias -> bf16 ; 1: +bias+resid -> f32 ; 2: +bias, gelu -> bf16
template<int EPI>
__global__ __launch_bounds__(256, 2)
void gemm_bt(const unsigned short* __restrict__ A,
             const unsigned short* __restrict__ Bt,
             const float* __restrict__ bias,
             const float* __restrict__ resid,
             void* __restrict__ outv,
             int M, int N, int K){
    __shared__ unsigned short lA[128 * 32];
    __shared__ unsigned short lB[128 * 32];
    const int t = threadIdx.x, w = t >> 6, l = t & 63, lr = l & 15, lg = l >> 4;
    const int nt = N >> 7;
    const int bm = blockIdx.x / nt, bn = blockIdx.x % nt;
    const int row0 = bm << 7, col0 = bn << 7;
    const int wr = w >> 1, wc = w & 1;

    f32x4 acc[4][4];
    #pragma unroll
    for (int i = 0; i < 4; i++)
        #pragma unroll
        for (int j = 0; j < 4; j++) acc[i][j] = (f32x4){0.f,0.f,0.f,0.f};

    const char* Ag = (const char*)(A + (size_t)(row0 + (t >> 2)) * K) + (t & 3) * 16;
    const char* Bg = (const char*)(Bt + (size_t)(col0 + (t >> 2)) * K) + (t & 3) * 16;
    const size_t rstep = (size_t)64 * K * 2;
    char* lAw = (char*)lA + w * 1024;
    char* lBw = (char*)lB + w * 1024;

    for (int k0 = 0; k0 < K; k0 += 32){
        size_t kb = (size_t)k0 * 2;
        gl_lds16(Ag + kb,          lAw);
        gl_lds16(Ag + kb + rstep,  lAw + 4096);
        gl_lds16(Bg + kb,          lBw);
        gl_lds16(Bg + kb + rstep,  lBw + 4096);
        __syncthreads();
        bf16x8 af[4], bfr[4];
        #pragma unroll
        for (int mi = 0; mi < 4; mi++)
            af[mi] = ldbf8(lA + (wr*64 + mi*16 + lr) * 32 + lg * 8);
        #pragma unroll
        for (int ni = 0; ni < 4; ni++)
            bfr[ni] = ldbf8(lB + (wc*64 + ni*16 + lr) * 32 + lg * 8);
        #pragma unroll
        for (int mi = 0; mi < 4; mi++)
            #pragma unroll
            for (int ni = 0; ni < 4; ni++)
                acc[mi][ni] = __builtin_amdgcn_mfma_f32_16x16x32_bf16(
                    af[mi], bfr[ni], acc[mi][ni], 0, 0, 0);
        __syncthreads();
    }

    float bcol[4];
    #pragma unroll
    for (int ni = 0; ni < 4; ni++) bcol[ni] = bias[col0 + wc*64 + ni*16 + lr];
    #pragma unroll
    for (int mi = 0; mi < 4; mi++){
        #pragma unroll
        for (int j = 0; j < 4; j++){
            int row = row0 + wr*64 + mi*16 + lg*4 + j;
            size_t base = (size_t)row * N + col0 + wc*64 + lr;
            #pragma unroll
            for (int ni = 0; ni < 4; ni++){
                float v = acc[mi][ni][j] + bcol[ni];
                size_t idx = base + (size_t)ni * 16;
                if (EPI == 0)      ((unsigned short*)outv)[idx] = f2bf(v);
                else if (EPI == 1) ((float*)outv)[idx] = v + resid[idx];
                else               ((unsigned short*)outv)[idx] = f2bf(gelu_tanh(v));
            }
        }
    }
}

// ---------------- V pre-transpose: qkv [tok][3C] -> vTg [bh][kt][64 d][80]
__global__ __launch_bounds__(256)
void vtrans(const unsigned short* __restrict__ qkv, unsigned short* __restrict__ vTg){
    __shared__ unsigned short lt[64][68];
    int kt = blockIdx.x & (NQT - 1);
    int bh = blockIdx.x >> 5;
    int h = bh & (TH - 1), b = bh >> 4;
    int t = threadIdx.x;
    int r = t >> 2, c4 = t & 3;
    const unsigned short* src = qkv + (size_t)(b*TT + kt*64 + r) * (3*TC) + 2*TC + h*THD;
    u16x8 a0 = *(const u16x8*)(src + c4*8);
    u16x8 a1 = *(const u16x8*)(src + 32 + c4*8);
    #pragma unroll
    for (int j = 0; j < 8; j++){
        lt[r][c4*8 + j]      = a0[j];
        lt[r][32 + c4*8 + j] = a1[j];
    }
    __syncthreads();
    int d = t >> 2;
    unsigned short* dst = vTg + ((size_t)bh * NQT + kt) * (64*80) + (size_t)d * 80;
    u16x8 o0, o1;
    #pragma unroll
    for (int j = 0; j < 8; j++){
        o0[j] = lt[c4*8 + j][d];
        o1[j] = lt[32 + c4*8 + j][d];
    }
    *(u16x8*)(dst + c4*8)      = o0;
    *(u16x8*)(dst + 32 + c4*8) = o1;
}

// ---------------- flash attention (causal), paired q-tiles for load balance
__global__ __launch_bounds__(256, 2)
void attn_kernel(const unsigned short* __restrict__ qkv,
                 const unsigned short* __restrict__ vTg,
                 unsigned short* __restrict__ attn_out){
    __shared__ unsigned short vT[2][64*80];     // double-buffered V^T tiles
    __shared__ unsigned short pl[4][2][16*88];  // per-wave P tiles (A,B)

    const int bid = blockIdx.x;
    const int pair = bid & 15;           // NQT/2 = 16 pairs
    const int bh = bid >> 4;
    const int h = bh & (TH - 1), b = bh >> 4;
    const int qA = pair, qB = NQT - 1 - pair;
    const int t = threadIdx.x, w = t >> 6, l = t & 63, lr = l & 15, lg = l >> 4;
    const float SC = 0.18033688011112042f;  // 0.125 * log2(e)

    const unsigned short* qbase = qkv + (size_t)(b*TT) * (3*TC) + h*THD;
    const unsigned short* kbase = qkv + (size_t)(b*TT) * (3*TC) + TC + h*THD;
    const unsigned short* vtb = vTg + (size_t)bh * (NQT * 64 * 80);

    const unsigned short* qra = qbase + (size_t)(qA*64 + w*16 + lr) * (3*TC);
    const unsigned short* qrb = qbase + (size_t)(qB*64 + w*16 + lr) * (3*TC);
    bf16x8 qA0 = ldbf8(qra + lg*8), qA1 = ldbf8(qra + 32 + lg*8);
    bf16x8 qB0 = ldbf8(qrb + lg*8), qB1 = ldbf8(qrb + 32 + lg*8);

    f32x4 oA[4], oB[4];
    float mA[4], lsA[4], mB[4], lsB[4];
    #pragma unroll
    for (int i = 0; i < 4; i++){
        oA[i] = (f32x4){0.f,0.f,0.f,0.f};
        oB[i] = (f32x4){0.f,0.f,0.f,0.f};
        mA[i] = -1e30f; lsA[i] = 0.f;
        mB[i] = -1e30f; lsB[i] = 0.f;
    }

    // stage one V^T tile (10240 B) into LDS buffer: waves 0,1 copy 3KB; 2,3 copy 2KB
    const int nstg  = (w < 2) ? 3 : 2;
    const int sbase = (w < 2) ? w*3072 : 6144 + (w - 2)*2048;
    auto stage = [&](int kt, int bufi){
        const char* src = (const char*)(vtb + (size_t)kt * (64*80));
        char* dst = (char*)vT[bufi];
        for (int c = 0; c < nstg; c++)
            gl_lds16(src + sbase + c*1024 + l*16, dst + sbase + c*1024);
    };

    // softmax update for one tile; s is pre-scaled (log2 domain) and pre-masked
    auto process_tile = [&](f32x4* s, float* m, float* ls, f32x4* o,
                            unsigned short* plw){
        float mloc[4];
        #pragma unroll
        for (int j = 0; j < 4; j++)
            mloc[j] = fmaxf(fmaxf(s[0][j], s[1][j]), fmaxf(s[2][j], s[3][j]));
        #pragma unroll
        for (int off = 1; off < 16; off <<= 1)
            #pragma unroll
            for (int j = 0; j < 4; j++)
                mloc[j] = fmaxf(mloc[j], __shfl_xor(mloc[j], off));
        float al[4];
        #pragma unroll
        for (int j = 0; j < 4; j++){
            float mn = fmaxf(m[j], mloc[j]);
            al[j] = exp2f(m[j] - mn);
            m[j] = mn;
        }
        float ps[4] = {0.f, 0.f, 0.f, 0.f};
        #pragma unroll
        for (int cb = 0; cb < 4; cb++)
            #pragma unroll
            for (int j = 0; j < 4; j++){
                float e = exp2f(s[cb][j] - m[j]);
                ps[j] += e;
                ((__bf16*)plw)[(lg*4 + j)*88 + cb*16 + lr] = (__bf16)e;
            }
        #pragma unroll
        for (int off = 1; off < 16; off <<= 1)
            #pragma unroll
            for (int j = 0; j < 4; j++)
                ps[j] += __shfl_xor(ps[j], off);
        #pragma unroll
        for (int j = 0; j < 4; j++) ls[j] = ls[j]*al[j] + ps[j];
        #pragma unroll
        for (int db = 0; db < 4; db++)
            #pragma unroll
            for (int j = 0; j < 4; j++) o[db][j] *= al[j];
    };

    auto pv = [&](const unsigned short* vbuf, const unsigned short* plw, f32x4* o){
        bf16x8 pa0 = ldbf8(plw + lr*88 + lg*8);
        bf16x8 pa1 = ldbf8(plw + lr*88 + 32 + lg*8);
        #pragma unroll
        for (int db = 0; db < 4; db++){
            bf16x8 v0 = ldbf8(vbuf + (db*16 + lr)*80 + lg*8);
            bf16x8 v1 = ldbf8(vbuf + (db*16 + lr)*80 + 32 + lg*8);
            o[db] = __builtin_amdgcn_mfma_f32_16x16x32_bf16(pa0, v0, o[db], 0,0,0);
            o[db] = __builtin_amdgcn_mfma_f32_16x16x32_bf16(pa1, v1, o[db], 0,0,0);
        }
    };

    stage(0, 0);

    for (int kt = 0; kt <= qB; ++kt){
        const bool doA = (kt <= qA);
        f32x4 sA[4], sB[4];
        #pragma unroll
        for (int cb = 0; cb < 4; cb++){
            const unsigned short* kb = kbase + (size_t)(kt*64 + cb*16 + lr) * (3*TC);
            bf16x8 k0 = ldbf8(kb + lg*8), k1 = ldbf8(kb + 32 + lg*8);
            f32x4 z = (f32x4){0.f,0.f,0.f,0.f};
            z = __builtin_amdgcn_mfma_f32_16x16x32_bf16(qB0, k0, z, 0,0,0);
            z = __builtin_amdgcn_mfma_f32_16x16x32_bf16(qB1, k1, z, 0,0,0);
            sB[cb] = z;
            if (doA){
                f32x4 za = (f32x4){0.f,0.f,0.f,0.f};
                za = __builtin_amdgcn_mfma_f32_16x16x32_bf16(qA0, k0, za, 0,0,0);
                za = __builtin_amdgcn_mfma_f32_16x16x32_bf16(qA1, k1, za, 0,0,0);
                sA[cb] = za;
            }
        }
        // scale + causal mask (diag tiles only)
        #pragma unroll
        for (int cb = 0; cb < 4; cb++)
            #pragma unroll
            for (int j = 0; j < 4; j++){
                float vb2 = sB[cb][j] * SC;
                if (kt == qB && (cb*16 + lr) > (w*16 + lg*4 + j)) vb2 = -1e30f;
                sB[cb][j] = vb2;
            }
        process_tile(sB, mB, lsB, oB, &pl[w][1][0]);
        if (doA){
            #pragma unroll
            for (int cb = 0; cb < 4; cb++)
                #pragma unroll
                for (int j = 0; j < 4; j++){
                    float va = sA[cb][j] * SC;
                    if (kt == qA && (cb*16 + lr) > (w*16 + lg*4 + j)) va = -1e30f;
                    sA[cb][j] = va;
                }
            process_tile(sA, mA, lsA, oA, &pl[w][0][0]);
        }

        __syncthreads();   // drains vmcnt(0): stage(kt) complete for all waves

        const unsigned short* vbuf = vT[kt & 1];
        pv(vbuf, &pl[w][1][0], oB);
        if (doA) pv(vbuf, &pl[w][0][0], oA);

        if (kt < qB) stage(kt + 1, (kt + 1) & 1);
    }

    __bf16* aout = (__bf16*)attn_out;
    #pragma unroll
    for (int j = 0; j < 4; j++){
        float invB = 1.f / lsB[j];
        float invA = 1.f / lsA[j];
        size_t tokB = (size_t)(b*TT + qB*64 + w*16 + lg*4 + j);
        size_t tokA = (size_t)(b*TT + qA*64 + w*16 + lg*4 + j);
        #pragma unroll
        for (int db = 0; db < 4; db++){
            aout[tokB*TC + h*THD + db*16 + lr] = (__bf16)(oB[db][j] * invB);
            aout[tokA*TC + h*THD + db*16 + lr] = (__bf16)(oA[db][j] * invA);
        }
    }
}

extern "C" void kernel_launch(void* const* d_in, const int* in_sizes, int n_in,
                              void* d_out, int out_size, void* d_ws, size_t ws_size,
                              hipStream_t stream){
    const float* x      = (const float*)d_in[0];
    const float* ln1_g  = (const float*)d_in[1];
    const float* ln1_b  = (const float*)d_in[2];
    const float* w_attn = (const float*)d_in[3];
    const float* b_attn = (const float*)d_in[4];
    const float* w_proj = (const float*)d_in[5];
    const float* b_proj = (const float*)d_in[6];
    const float* ln2_g  = (const float*)d_in[7];
    const float* ln2_b  = (const float*)d_in[8];
    const float* w_fc   = (const float*)d_in[9];
    const float* b_fc   = (const float*)d_in[10];
    const float* w_fc2  = (const float*)d_in[11];
    const float* b_fc2  = (const float*)d_in[12];
    float* out = (float*)d_out;

    char* ws = (char*)d_ws;
    size_t off = 0;
    auto alloc = [&](size_t bytes) -> void* {
        void* p = ws + off;
        off += (bytes + 255) & ~(size_t)255;
        return p;
    };
    unsigned short* wattnT = (unsigned short*)alloc((size_t)3072*1024*2);
    unsigned short* wprojT = (unsigned short*)alloc((size_t)1024*1024*2);
    unsigned short* wfcT   = (unsigned short*)alloc((size_t)4096*1024*2);
    unsigned short* wfc2T  = (unsigned short*)alloc((size_t)1024*4096*2);
    unsigned short* xn1    = (unsigned short*)alloc((size_t)TM*TC*2);
    unsigned short* qkvb   = (unsigned short*)alloc((size_t)TM*3*TC*2);
    unsigned short* attnO  = (unsigned short*)alloc((size_t)TM*TC*2);
    float*          resid1 = (float*)alloc((size_t)TM*TC*4);
    unsigned short* xn2    = (unsigned short*)alloc((size_t)TM*TC*2);
    unsigned short* hbuf   = (unsigned short*)alloc((size_t)TM*4*TC*2);
    unsigned short* vTg    = (unsigned short*)alloc((size_t)TB*TH*NQT*64*80*2);

    dim3 tb(32, 8, 1);
    convert_transpose<<<dim3(3072/32, 1024/32), tb, 0, stream>>>(w_attn, wattnT, 1024, 3072);
    convert_transpose<<<dim3(1024/32, 1024/32), tb, 0, stream>>>(w_proj, wprojT, 1024, 1024);
    convert_transpose<<<dim3(4096/32, 1024/32), tb, 0, stream>>>(w_fc,   wfcT,   1024, 4096);
    convert_transpose<<<dim3(1024/32, 4096/32), tb, 0, stream>>>(w_fc2,  wfc2T,  4096, 1024);

    ln_kernel<<<TM, 256, 0, stream>>>(x, ln1_g, ln1_b, xn1);

    gemm_bt<0><<<(TM/128)*(3072/128), 256, 0, stream>>>(
        xn1, wattnT, b_attn, nullptr, qkvb, TM, 3072, 1024);

    vtrans<<<TB*TH*NQT, 256, 0, stream>>>(qkvb, vTg);

    attn_kernel<<<TB*TH*(NQT/2), 256, 0, stream>>>(qkvb, vTg, attnO);

    gemm_bt<1><<<(TM/128)*(1024/128), 256, 0, stream>>>(
        attnO, wprojT, b_proj, x, resid1, TM, 1024, 1024);

    ln_kernel<<<TM, 256, 0, stream>>>(resid1, ln2_g, ln2_b, xn2);

    gemm_bt<2><<<(TM/128)*(4096/128), 256, 0, stream>>>(
        xn2, wfcT, b_fc, nullptr, hbuf, TM, 4096, 1024);

    gemm_bt<1><<<(TM/128)*(1024/128), 256, 0, stream>>>(
        hbuf, wfc2T, b_fc2, resid1, out, TM, 1024, 4096);
}

// Round 3
// 321.696 us; speedup vs baseline: 1.1185x; 1.0339x over previous
//
#include <hip/hip_runtime.h>
#include <math.h>

#define TB 2
#define TT 2048
#define TC 1024
#define TH 16
#define THD 64
#define TM (TB*TT)   // 4096 tokens
#define NQT 32       // TT/64 kv/q tiles

typedef __bf16 bf16x8 __attribute__((ext_vector_type(8)));
typedef float f32x4 __attribute__((ext_vector_type(4)));
typedef unsigned short u16x8 __attribute__((ext_vector_type(8)));
typedef unsigned short u16x4 __attribute__((ext_vector_type(4)));

__device__ __forceinline__ unsigned short f2bf(float f){
    unsigned int u = __builtin_bit_cast(unsigned int, f);
    u = (u + 0x7FFFu + ((u >> 16) & 1u)) >> 16;
    return (unsigned short)u;
}
__device__ __forceinline__ bf16x8 ldbf8(const unsigned short* p){
    return __builtin_bit_cast(bf16x8, *(const u16x8*)p);
}
__device__ __forceinline__ void gl_lds16(const void* g, void* l){
    __builtin_amdgcn_global_load_lds(
        (const __attribute__((address_space(1))) unsigned int*)g,
        (__attribute__((address_space(3))) unsigned int*)l,
        16, 0, 0);
}
__device__ __forceinline__ float gelu_tanh(float v){
    float u = 2.0f * 0.7978845608028654f * (v + 0.044715f * v * v * v);
    u = fminf(fmaxf(u, -30.f), 30.f);
    float e = __expf(u);
    return 0.5f * v * (1.f + (e - 1.f) / (e + 1.f));
}

// ---------------- weight convert+transpose: in [K][N] f32 -> out [N][K] bf16
__global__ __launch_bounds__(256)
void convert_transpose(const float* __restrict__ in, unsigned short* __restrict__ out,
                       int K, int N){
    __shared__ float tile[32][33];
    int tx = threadIdx.x, ty = threadIdx.y;
    int n0 = blockIdx.x * 32, k0 = blockIdx.y * 32;
    #pragma unroll
    for (int i = 0; i < 4; i++)
        tile[ty + 8*i][tx] = in[(size_t)(k0 + ty + 8*i) * N + n0 + tx];
    __syncthreads();
    #pragma unroll
    for (int i = 0; i < 4; i++)
        out[(size_t)(n0 + ty + 8*i) * K + k0 + tx] = f2bf(tile[tx][ty + 8*i]);
}

// ---------------- layernorm: x f32 [.][1024] -> y bf16
__global__ __launch_bounds__(256)
void ln_kernel(const float* __restrict__ x, const float* __restrict__ g,
               const float* __restrict__ be, unsigned short* __restrict__ y){
    const int row = blockIdx.x, t = threadIdx.x;
    const float4* xr = (const float4*)(x + (size_t)row * TC);
    float4 v = xr[t];
    float s  = v.x + v.y + v.z + v.w;
    float s2 = v.x*v.x + v.y*v.y + v.z*v.z + v.w*v.w;
    #pragma unroll
    for (int off = 32; off; off >>= 1){
        s  += __shfl_down(s,  off);
        s2 += __shfl_down(s2, off);
    }
    __shared__ float red[8];
    int l = t & 63, wv = t >> 6;
    if (l == 0){ red[wv] = s; red[4 + wv] = s2; }
    __syncthreads();
    float S  = red[0] + red[1] + red[2] + red[3];
    float S2 = red[4] + red[5] + red[6] + red[7];
    float mu = S * (1.f / TC);
    float var = S2 * (1.f / TC) - mu * mu;
    float rs = rsqrtf(var + 1e-5f);
    int c = t * 4;
    float4 gg = *(const float4*)(g + c);
    float4 bb = *(const float4*)(be + c);
    u16x4 o;
    o[0] = f2bf((v.x - mu) * rs * gg.x + bb.x);
    o[1] = f2bf((v.y - mu) * rs * gg.y + bb.y);
    o[2] = f2bf((v.z - mu) * rs * gg.z + bb.z);
    o[3] = f2bf((v.w - mu) * rs * gg.w + bb.w);
    *(u16x4*)(y + (size_t)row * TC + c) = o;
}

// ---------------- GEMM: A [M][K] bf16, Bt [N][K] bf16 -> out [M][N]
// EPI 0: +bias -> bf16 ; 1: +bias+resid -> f32 ; 2: +bias, gelu -> bf16
template<int EPI>
__global__ __launch_bounds__(256, 2)
void gemm_bt(const unsigned short* __restrict__ A,
             const unsigned short* __restrict__ Bt,
             const float* __restrict__ bias,
             const float* __restrict__ resid,
             void* __restrict__ outv,
             int M, int N, int K){
    __shared__ unsigned short lA[128 * 32];
    __shared__ unsigned short lB[128 * 32];
    const int t = threadIdx.x, w = t >> 6, l = t & 63, lr = l & 15, lg = l >> 4;
    const int nt = N >> 7;
    const int bm = blockIdx.x / nt, bn = blockIdx.x % nt;
    const int row0 = bm << 7, col0 = bn << 7;
    const int wr = w >> 1, wc = w & 1;

    f32x4 acc[4][4];
    #pragma unroll
    for (int i = 0; i < 4; i++)
        #pragma unroll
        for (int j = 0; j < 4; j++) acc[i][j] = (f32x4){0.f,0.f,0.f,0.f};

    const char* Ag = (const char*)(A + (size_t)(row0 + (t >> 2)) * K) + (t & 3) * 16;
    const char* Bg = (const char*)(Bt + (size_t)(col0 + (t >> 2)) * K) + (t & 3) * 16;
    const size_t rstep = (size_t)64 * K * 2;
    char* lAw = (char*)lA + w * 1024;
    char* lBw = (char*)lB + w * 1024;

    for (int k0 = 0; k0 < K; k0 += 32){
        size_t kb = (size_t)k0 * 2;
        gl_lds16(Ag + kb,          lAw);
        gl_lds16(Ag + kb + rstep,  lAw + 4096);
        gl_lds16(Bg + kb,          lBw);
        gl_lds16(Bg + kb + rstep,  lBw + 4096);
        __syncthreads();
        bf16x8 af[4], bfr[4];
        #pragma unroll
        for (int mi = 0; mi < 4; mi++)
            af[mi] = ldbf8(lA + (wr*64 + mi*16 + lr) * 32 + lg * 8);
        #pragma unroll
        for (int ni = 0; ni < 4; ni++)
            bfr[ni] = ldbf8(lB + (wc*64 + ni*16 + lr) * 32 + lg * 8);
        #pragma unroll
        for (int mi = 0; mi < 4; mi++)
            #pragma unroll
            for (int ni = 0; ni < 4; ni++)
                acc[mi][ni] = __builtin_amdgcn_mfma_f32_16x16x32_bf16(
                    af[mi], bfr[ni], acc[mi][ni], 0, 0, 0);
        __syncthreads();
    }

    float bcol[4];
    #pragma unroll
    for (int ni = 0; ni < 4; ni++) bcol[ni] = bias[col0 + wc*64 + ni*16 + lr];
    #pragma unroll
    for (int mi = 0; mi < 4; mi++){
        #pragma unroll
        for (int j = 0; j < 4; j++){
            int row = row0 + wr*64 + mi*16 + lg*4 + j;
            size_t base = (size_t)row * N + col0 + wc*64 + lr;
            #pragma unroll
            for (int ni = 0; ni < 4; ni++){
                float v = acc[mi][ni][j] + bcol[ni];
                size_t idx = base + (size_t)ni * 16;
                if (EPI == 0)      ((unsigned short*)outv)[idx] = f2bf(v);
                else if (EPI == 1) ((float*)outv)[idx] = v + resid[idx];
                else               ((unsigned short*)outv)[idx] = f2bf(gelu_tanh(v));
            }
        }
    }
}

// ---------------- V pre-transpose: qkv [tok][3C] -> vTg [bh][kt][64 d][80]
__global__ __launch_bounds__(256)
void vtrans(const unsigned short* __restrict__ qkv, unsigned short* __restrict__ vTg){
    __shared__ unsigned short lt[64][68];
    int kt = blockIdx.x & (NQT - 1);
    int bh = blockIdx.x >> 5;
    int h = bh & (TH - 1), b = bh >> 4;
    int t = threadIdx.x;
    int r = t >> 2, c4 = t & 3;
    const unsigned short* src = qkv + (size_t)(b*TT + kt*64 + r) * (3*TC) + 2*TC + h*THD;
    u16x8 a0 = *(const u16x8*)(src + c4*8);
    u16x8 a1 = *(const u16x8*)(src + 32 + c4*8);
    #pragma unroll
    for (int j = 0; j < 8; j++){
        lt[r][c4*8 + j]      = a0[j];
        lt[r][32 + c4*8 + j] = a1[j];
    }
    __syncthreads();
    int d = t >> 2;
    unsigned short* dst = vTg + ((size_t)bh * NQT + kt) * (64*80) + (size_t)d * 80;
    u16x8 o0, o1;
    #pragma unroll
    for (int j = 0; j < 8; j++){
        o0[j] = lt[c4*8 + j][d];
        o1[j] = lt[32 + c4*8 + j][d];
    }
    *(u16x8*)(dst + c4*8)      = o0;
    *(u16x8*)(dst + 32 + c4*8) = o1;
}

// ---------------- flash attention (causal), paired q-tiles, barrier-free
__global__ __launch_bounds__(256, 2)
void attn_kernel(const unsigned short* __restrict__ qkv,
                 const unsigned short* __restrict__ vTg,
                 unsigned short* __restrict__ attn_out){
    __shared__ unsigned short pl[4][2][16*88];  // per-wave P tiles (A,B) — no barriers

    const int bid = blockIdx.x;
    const int pair = bid & 15;           // NQT/2 = 16 pairs
    const int bh = bid >> 4;
    const int h = bh & (TH - 1), b = bh >> 4;
    const int qA = pair, qB = NQT - 1 - pair;
    const int t = threadIdx.x, w = t >> 6, l = t & 63, lr = l & 15, lg = l >> 4;
    const float SC = 0.18033688011112042f;  // 0.125 * log2(e)

    const unsigned short* qbase = qkv + (size_t)(b*TT) * (3*TC) + h*THD;
    const unsigned short* kbase = qkv + (size_t)(b*TT) * (3*TC) + TC + h*THD;
    const unsigned short* vtb = vTg + (size_t)bh * (NQT * 64 * 80);

    const unsigned short* qra = qbase + (size_t)(qA*64 + w*16 + lr) * (3*TC);
    const unsigned short* qrb = qbase + (size_t)(qB*64 + w*16 + lr) * (3*TC);
    bf16x8 qA0 = ldbf8(qra + lg*8), qA1 = ldbf8(qra + 32 + lg*8);
    bf16x8 qB0 = ldbf8(qrb + lg*8), qB1 = ldbf8(qrb + 32 + lg*8);

    // all-ones B fragment: o[4] accumulates the softmax denominator via MFMA
    bf16x8 ones;
    #pragma unroll
    for (int i = 0; i < 8; i++) ones[i] = (__bf16)1.0f;

    f32x4 oA[5], oB[5];
    float mA[4], mB[4];
    #pragma unroll
    for (int i = 0; i < 5; i++){
        oA[i] = (f32x4){0.f,0.f,0.f,0.f};
        oB[i] = (f32x4){0.f,0.f,0.f,0.f};
    }
    #pragma unroll
    for (int i = 0; i < 4; i++){ mA[i] = -1e30f; mB[i] = -1e30f; }

    // softmax update: s pre-scaled (log2 domain) + pre-masked; writes P to plw
    auto process_tile = [&](f32x4* s, float* m, f32x4* o, unsigned short* plw){
        float mloc[4];
        #pragma unroll
        for (int j = 0; j < 4; j++)
            mloc[j] = fmaxf(fmaxf(s[0][j], s[1][j]), fmaxf(s[2][j], s[3][j]));
        #pragma unroll
        for (int off = 1; off < 16; off <<= 1)
            #pragma unroll
            for (int j = 0; j < 4; j++)
                mloc[j] = fmaxf(mloc[j], __shfl_xor(mloc[j], off));
        float al[4];
        #pragma unroll
        for (int j = 0; j < 4; j++){
            float mn = fmaxf(m[j], mloc[j]);
            al[j] = exp2f(m[j] - mn);
            m[j] = mn;
        }
        #pragma unroll
        for (int cb = 0; cb < 4; cb++)
            #pragma unroll
            for (int j = 0; j < 4; j++){
                float e = exp2f(s[cb][j] - m[j]);
                ((__bf16*)plw)[(lg*4 + j)*88 + cb*16 + lr] = (__bf16)e;
            }
        #pragma unroll
        for (int db = 0; db < 5; db++)
            #pragma unroll
            for (int j = 0; j < 4; j++) o[db][j] *= al[j];
    };

    auto pv = [&](const bf16x8* v0, const bf16x8* v1, const unsigned short* plw,
                  f32x4* o){
        bf16x8 pa0 = ldbf8(plw + lr*88 + lg*8);
        bf16x8 pa1 = ldbf8(plw + lr*88 + 32 + lg*8);
        #pragma unroll
        for (int db = 0; db < 4; db++){
            o[db] = __builtin_amdgcn_mfma_f32_16x16x32_bf16(pa0, v0[db], o[db], 0,0,0);
            o[db] = __builtin_amdgcn_mfma_f32_16x16x32_bf16(pa1, v1[db], o[db], 0,0,0);
        }
        o[4] = __builtin_amdgcn_mfma_f32_16x16x32_bf16(pa0, ones, o[4], 0,0,0);
        o[4] = __builtin_amdgcn_mfma_f32_16x16x32_bf16(pa1, ones, o[4], 0,0,0);
    };

    for (int kt = 0; kt <= qB; ++kt){
        const bool doA = (kt <= qA);
        // V fragments for this tile — issued early, consumed at PV (latency hidden)
        const unsigned short* vt = vtb + (size_t)kt * (64*80);
        bf16x8 vf0[4], vf1[4];
        #pragma unroll
        for (int db = 0; db < 4; db++){
            vf0[db] = ldbf8(vt + (db*16 + lr)*80 + lg*8);
            vf1[db] = ldbf8(vt + (db*16 + lr)*80 + 32 + lg*8);
        }
        // S = Q K^T (B always; A while active)
        f32x4 sA[4], sB[4];
        #pragma unroll
        for (int cb = 0; cb < 4; cb++){
            const unsigned short* kb = kbase + (size_t)(kt*64 + cb*16 + lr) * (3*TC);
            bf16x8 k0 = ldbf8(kb + lg*8), k1 = ldbf8(kb + 32 + lg*8);
            f32x4 z = (f32x4){0.f,0.f,0.f,0.f};
            z = __builtin_amdgcn_mfma_f32_16x16x32_bf16(qB0, k0, z, 0,0,0);
            z = __builtin_amdgcn_mfma_f32_16x16x32_bf16(qB1, k1, z, 0,0,0);
            sB[cb] = z;
            if (doA){
                f32x4 za = (f32x4){0.f,0.f,0.f,0.f};
                za = __builtin_amdgcn_mfma_f32_16x16x32_bf16(qA0, k0, za, 0,0,0);
                za = __builtin_amdgcn_mfma_f32_16x16x32_bf16(qA1, k1, za, 0,0,0);
                sA[cb] = za;
            }
        }
        // scale + causal mask (diag tiles only)
        #pragma unroll
        for (int cb = 0; cb < 4; cb++)
            #pragma unroll
            for (int j = 0; j < 4; j++){
                float vb2 = sB[cb][j] * SC;
                if (kt == qB && (cb*16 + lr) > (w*16 + lg*4 + j)) vb2 = -1e30f;
                sB[cb][j] = vb2;
            }
        process_tile(sB, mB, oB, &pl[w][1][0]);
        pv(vf0, vf1, &pl[w][1][0], oB);   // PV-B MFMAs execute under softmax-A VALU
        if (doA){
            #pragma unroll
            for (int cb = 0; cb < 4; cb++)
                #pragma unroll
                for (int j = 0; j < 4; j++){
                    float va = sA[cb][j] * SC;
                    if (kt == qA && (cb*16 + lr) > (w*16 + lg*4 + j)) va = -1e30f;
                    sA[cb][j] = va;
                }
            process_tile(sA, mA, oA, &pl[w][0][0]);
            pv(vf0, vf1, &pl[w][0][0], oA);
        }
    }

    __bf16* aout = (__bf16*)attn_out;
    #pragma unroll
    for (int j = 0; j < 4; j++){
        float invB = 1.f / oB[4][j];
        float invA = 1.f / oA[4][j];
        size_t tokB = (size_t)(b*TT + qB*64 + w*16 + lg*4 + j);
        size_t tokA = (size_t)(b*TT + qA*64 + w*16 + lg*4 + j);
        #pragma unroll
        for (int db = 0; db < 4; db++){
            aout[tokB*TC + h*THD + db*16 + lr] = (__bf16)(oB[db][j] * invB);
            aout[tokA*TC + h*THD + db*16 + lr] = (__bf16)(oA[db][j] * invA);
        }
    }
}

extern "C" void kernel_launch(void* const* d_in, const int* in_sizes, int n_in,
                              void* d_out, int out_size, void* d_ws, size_t ws_size,
                              hipStream_t stream){
    const float* x      = (const float*)d_in[0];
    const float* ln1_g  = (const float*)d_in[1];
    const float* ln1_b  = (const float*)d_in[2];
    const float* w_attn = (const float*)d_in[3];
    const float* b_attn = (const float*)d_in[4];
    const float* w_proj = (const float*)d_in[5];
    const float* b_proj = (const float*)d_in[6];
    const float* ln2_g  = (const float*)d_in[7];
    const float* ln2_b  = (const float*)d_in[8];
    const float* w_fc   = (const float*)d_in[9];
    const float* b_fc   = (const float*)d_in[10];
    const float* w_fc2  = (const float*)d_in[11];
    const float* b_fc2  = (const float*)d_in[12];
    float* out = (float*)d_out;

    char* ws = (char*)d_ws;
    size_t off = 0;
    auto alloc = [&](size_t bytes) -> void* {
        void* p = ws + off;
        off += (bytes + 255) & ~(size_t)255;
        return p;
    };
    unsigned short* wattnT = (unsigned short*)alloc((size_t)3072*1024*2);
    unsigned short* wprojT = (unsigned short*)alloc((size_t)1024*1024*2);
    unsigned short* wfcT   = (unsigned short*)alloc((size_t)4096*1024*2);
    unsigned short* wfc2T  = (unsigned short*)alloc((size_t)1024*4096*2);
    unsigned short* xn1    = (unsigned short*)alloc((size_t)TM*TC*2);
    unsigned short* qkvb   = (unsigned short*)alloc((size_t)TM*3*TC*2);
    unsigned short* attnO  = (unsigned short*)alloc((size_t)TM*TC*2);
    float*          resid1 = (float*)alloc((size_t)TM*TC*4);
    unsigned short* xn2    = (unsigned short*)alloc((size_t)TM*TC*2);
    unsigned short* hbuf   = (unsigned short*)alloc((size_t)TM*4*TC*2);
    unsigned short* vTg    = (unsigned short*)alloc((size_t)TB*TH*NQT*64*80*2);

    dim3 tb(32, 8, 1);
    convert_transpose<<<dim3(3072/32, 1024/32), tb, 0, stream>>>(w_attn, wattnT, 1024, 3072);
    convert_transpose<<<dim3(1024/32, 1024/32), tb, 0, stream>>>(w_proj, wprojT, 1024, 1024);
    convert_transpose<<<dim3(4096/32, 1024/32), tb, 0, stream>>>(w_fc,   wfcT,   1024, 4096);
    convert_transpose<<<dim3(1024/32, 4096/32), tb, 0, stream>>>(w_fc2,  wfc2T,  4096, 1024);

    ln_kernel<<<TM, 256, 0, stream>>>(x, ln1_g, ln1_b, xn1);

    gemm_bt<0><<<(TM/128)*(3072/128), 256, 0, stream>>>(
        xn1, wattnT, b_attn, nullptr, qkvb, TM, 3072, 1024);

    vtrans<<<TB*TH*NQT, 256, 0, stream>>>(qkvb, vTg);

    attn_kernel<<<TB*TH*(NQT/2), 256, 0, stream>>>(qkvb, vTg, attnO);

    gemm_bt<1><<<(TM/128)*(1024/128), 256, 0, stream>>>(
        attnO, wprojT, b_proj, x, resid1, TM, 1024, 1024);

    ln_kernel<<<TM, 256, 0, stream>>>(resid1, ln2_g, ln2_b, xn2);

    gemm_bt<2><<<(TM/128)*(4096/128), 256, 0, stream>>>(
        xn2, wfcT, b_fc, nullptr, hbuf, TM, 4096, 1024);

    gemm_bt<1><<<(TM/128)*(1024/128), 256, 0, stream>>>(
        hbuf, wfc2T, b_fc2, resid1, out, TM, 1024, 4096);
}

// Round 4
// 318.122 us; speedup vs baseline: 1.1310x; 1.0112x over previous
//
#include <hip/hip_runtime.h>
#include <math.h>

#define TB 2
#define TT 2048
#define TC 1024
#define TH 16
#define THD 64
#define TM (TB*TT)   // 4096 tokens
#define NQT 32       // TT/64 kv/q tiles

typedef __bf16 bf16x8 __attribute__((ext_vector_type(8)));
typedef float f32x4 __attribute__((ext_vector_type(4)));
typedef unsigned short u16x8 __attribute__((ext_vector_type(8)));
typedef unsigned short u16x4 __attribute__((ext_vector_type(4)));

__device__ __forceinline__ unsigned short f2bf(float f){
    unsigned int u = __builtin_bit_cast(unsigned int, f);
    u = (u + 0x7FFFu + ((u >> 16) & 1u)) >> 16;
    return (unsigned short)u;
}
__device__ __forceinline__ bf16x8 ldbf8(const unsigned short* p){
    return __builtin_bit_cast(bf16x8, *(const u16x8*)p);
}
__device__ __forceinline__ void gl_lds16(const void* g, void* l){
    __builtin_amdgcn_global_load_lds(
        (const __attribute__((address_space(1))) unsigned int*)g,
        (__attribute__((address_space(3))) unsigned int*)l,
        16, 0, 0);
}
__device__ __forceinline__ float gelu_tanh(float v){
    float u = 2.0f * 0.7978845608028654f * (v + 0.044715f * v * v * v);
    u = fminf(fmaxf(u, -30.f), 30.f);
    float e = __expf(u);
    return 0.5f * v * (1.f + (e - 1.f) / (e + 1.f));
}

// ---------------- weight convert+transpose: in [K][N] f32 -> out [N][K] bf16
__global__ __launch_bounds__(256)
void convert_transpose(const float* __restrict__ in, unsigned short* __restrict__ out,
                       int K, int N){
    __shared__ float tile[32][33];
    int tx = threadIdx.x, ty = threadIdx.y;
    int n0 = blockIdx.x * 32, k0 = blockIdx.y * 32;
    #pragma unroll
    for (int i = 0; i < 4; i++)
        tile[ty + 8*i][tx] = in[(size_t)(k0 + ty + 8*i) * N + n0 + tx];
    __syncthreads();
    #pragma unroll
    for (int i = 0; i < 4; i++)
        out[(size_t)(n0 + ty + 8*i) * K + k0 + tx] = f2bf(tile[tx][ty + 8*i]);
}

// ---------------- layernorm: x f32 [.][1024] -> y bf16
__global__ __launch_bounds__(256)
void ln_kernel(const float* __restrict__ x, const float* __restrict__ g,
               const float* __restrict__ be, unsigned short* __restrict__ y){
    const int row = blockIdx.x, t = threadIdx.x;
    const float4* xr = (const float4*)(x + (size_t)row * TC);
    float4 v = xr[t];
    float s  = v.x + v.y + v.z + v.w;
    float s2 = v.x*v.x + v.y*v.y + v.z*v.z + v.w*v.w;
    #pragma unroll
    for (int off = 32; off; off >>= 1){
        s  += __shfl_down(s,  off);
        s2 += __shfl_down(s2, off);
    }
    __shared__ float red[8];
    int l = t & 63, wv = t >> 6;
    if (l == 0){ red[wv] = s; red[4 + wv] = s2; }
    __syncthreads();
    float S  = red[0] + red[1] + red[2] + red[3];
    float S2 = red[4] + red[5] + red[6] + red[7];
    float mu = S * (1.f / TC);
    float var = S2 * (1.f / TC) - mu * mu;
    float rs = rsqrtf(var + 1e-5f);
    int c = t * 4;
    float4 gg = *(const float4*)(g + c);
    float4 bb = *(const float4*)(be + c);
    u16x4 o;
    o[0] = f2bf((v.x - mu) * rs * gg.x + bb.x);
    o[1] = f2bf((v.y - mu) * rs * gg.y + bb.y);
    o[2] = f2bf((v.z - mu) * rs * gg.z + bb.z);
    o[3] = f2bf((v.w - mu) * rs * gg.w + bb.w);
    *(u16x4*)(y + (size_t)row * TC + c) = o;
}

// ---------------- 128x128 GEMM (m97 structure) + XCD swizzle
// EPI 0: +bias -> bf16 ; 1: +bias+resid -> f32 ; 2: +bias, gelu -> bf16
template<int EPI>
__global__ __launch_bounds__(256, 2)
void gemm_bt(const unsigned short* __restrict__ A,
             const unsigned short* __restrict__ Bt,
             const float* __restrict__ bias,
             const float* __restrict__ resid,
             void* __restrict__ outv,
             int M, int N, int K){
    __shared__ unsigned short lA[128 * 32];
    __shared__ unsigned short lB[128 * 32];
    const int t = threadIdx.x, w = t >> 6, l = t & 63, lr = l & 15, lg = l >> 4;
    const int nt = N >> 7;
    const int nwg = (M >> 7) * nt;
    const int bid = blockIdx.x;
    const int wg = (nwg & 7) ? bid : ((bid & 7) * (nwg >> 3) + (bid >> 3));
    const int bm = wg / nt, bn = wg % nt;
    const int row0 = bm << 7, col0 = bn << 7;
    const int wr = w >> 1, wc = w & 1;

    f32x4 acc[4][4];
    #pragma unroll
    for (int i = 0; i < 4; i++)
        #pragma unroll
        for (int j = 0; j < 4; j++) acc[i][j] = (f32x4){0.f,0.f,0.f,0.f};

    const char* Ag = (const char*)(A + (size_t)(row0 + (t >> 2)) * K) + (t & 3) * 16;
    const char* Bg = (const char*)(Bt + (size_t)(col0 + (t >> 2)) * K) + (t & 3) * 16;
    const size_t rstep = (size_t)64 * K * 2;
    char* lAw = (char*)lA + w * 1024;
    char* lBw = (char*)lB + w * 1024;

    for (int k0 = 0; k0 < K; k0 += 32){
        size_t kb = (size_t)k0 * 2;
        gl_lds16(Ag + kb,          lAw);
        gl_lds16(Ag + kb + rstep,  lAw + 4096);
        gl_lds16(Bg + kb,          lBw);
        gl_lds16(Bg + kb + rstep,  lBw + 4096);
        __syncthreads();
        bf16x8 af[4], bfr[4];
        #pragma unroll
        for (int mi = 0; mi < 4; mi++)
            af[mi] = ldbf8(lA + (wr*64 + mi*16 + lr) * 32 + lg * 8);
        #pragma unroll
        for (int ni = 0; ni < 4; ni++)
            bfr[ni] = ldbf8(lB + (wc*64 + ni*16 + lr) * 32 + lg * 8);
        #pragma unroll
        for (int mi = 0; mi < 4; mi++)
            #pragma unroll
            for (int ni = 0; ni < 4; ni++)
                acc[mi][ni] = __builtin_amdgcn_mfma_f32_16x16x32_bf16(
                    af[mi], bfr[ni], acc[mi][ni], 0, 0, 0);
        __syncthreads();
    }

    float bcol[4];
    #pragma unroll
    for (int ni = 0; ni < 4; ni++) bcol[ni] = bias[col0 + wc*64 + ni*16 + lr];
    #pragma unroll
    for (int mi = 0; mi < 4; mi++){
        #pragma unroll
        for (int j = 0; j < 4; j++){
            int row = row0 + wr*64 + mi*16 + lg*4 + j;
            size_t base = (size_t)row * N + col0 + wc*64 + lr;
            #pragma unroll
            for (int ni = 0; ni < 4; ni++){
                float v = acc[mi][ni][j] + bcol[ni];
                size_t idx = base + (size_t)ni * 16;
                if (EPI == 0)      ((unsigned short*)outv)[idx] = f2bf(v);
                else if (EPI == 1) ((float*)outv)[idx] = v + resid[idx];
                else               ((unsigned short*)outv)[idx] = f2bf(gelu_tanh(v));
            }
        }
    }
}

// ---------------- 256x256 8-phase GEMM (T2+T3+T4+T5), BK=64, 8 waves
// LDS swizzle: 16B slot ^= (row&7), applied pre-swizzled on global src + on ds_read.
template<int P>
__device__ __forceinline__ void gphase(const unsigned short* bufA, const unsigned short* bufB,
                                       f32x4 (&acc)[8][4], int wm, int wn,
                                       int lr, int lg, int sl0, int sl1){
    constexpr int mh = P >> 1, nh = P & 1;
    bf16x8 af[4][2], bfr[2][2];
    #pragma unroll
    for (int i = 0; i < 4; i++){
        int lrow = (wm*128 + (mh*4 + i)*16 + lr) * 64;
        af[i][0] = ldbf8(bufA + lrow + sl0);
        af[i][1] = ldbf8(bufA + lrow + sl1);
    }
    #pragma unroll
    for (int i = 0; i < 2; i++){
        int brow = (wn*64 + (nh*2 + i)*16 + lr) * 64;
        bfr[i][0] = ldbf8(bufB + brow + sl0);
        bfr[i][1] = ldbf8(bufB + brow + sl1);
    }
    __builtin_amdgcn_s_setprio(1);
    #pragma unroll
    for (int i = 0; i < 4; i++)
        #pragma unroll
        for (int j = 0; j < 2; j++){
            acc[mh*4+i][nh*2+j] = __builtin_amdgcn_mfma_f32_16x16x32_bf16(
                af[i][0], bfr[j][0], acc[mh*4+i][nh*2+j], 0, 0, 0);
            acc[mh*4+i][nh*2+j] = __builtin_amdgcn_mfma_f32_16x16x32_bf16(
                af[i][1], bfr[j][1], acc[mh*4+i][nh*2+j], 0, 0, 0);
        }
    __builtin_amdgcn_s_setprio(0);
}

template<int EPI>  // 0: +bias->bf16 ; 2: +bias,gelu->bf16
__global__ __launch_bounds__(512, 2)
void gemm256(const unsigned short* __restrict__ A,
             const unsigned short* __restrict__ Bt,
             const float* __restrict__ bias,
             void* __restrict__ outv,
             int M, int N, int K){
    __shared__ unsigned short lds[2][2][256*64];  // [buf][A,B][row*64+col] bf16, 128 KiB
    const int t = threadIdx.x;
    const int w = t >> 6, l = t & 63, lr = l & 15, lg = l >> 4;
    const int wm = w >> 2, wn = w & 3;
    const int lr7 = lr & 7;
    const int sl0 = (lg ^ lr7) << 3;          // kh=0 swizzled 16B slot (elems)
    const int sl1 = ((4 + lg) ^ lr7) << 3;    // kh=1
    const int nbn = N >> 8;
    const int nwg = (M >> 8) * nbn;
    const int bid = blockIdx.x;
    const int wg = (nwg & 7) ? bid : ((bid & 7) * (nwg >> 3) + (bid >> 3));
    const int bm = wg / nbn, bn = wg % nbn;
    const size_t row0 = (size_t)bm << 8, col0 = (size_t)bn << 8;
    const int NT = K >> 6;

    f32x4 acc[8][4];
    #pragma unroll
    for (int i = 0; i < 8; i++)
        #pragma unroll
        for (int j = 0; j < 4; j++) acc[i][j] = (f32x4){0.f,0.f,0.f,0.f};

    // staging: seg = t + c*512; row=seg>>3 (0..255); logical slot = (seg&7)^(row&7)
    int rowc[4], slogc[4];
    #pragma unroll
    for (int c = 0; c < 4; c++){
        int seg = t + (c << 9);
        rowc[c]  = seg >> 3;
        slogc[c] = (((seg & 7) ^ ((seg >> 3) & 7)) << 3);
    }
    const unsigned short* Abase = A  + row0 * K;
    const unsigned short* Bbase = Bt + col0 * K;
    auto stage = [&](int buf, int kt, int c){
        int seg = t + (c << 9);
        const unsigned short* sa = Abase + (size_t)rowc[c] * K + kt*64 + slogc[c];
        const unsigned short* sb = Bbase + (size_t)rowc[c] * K + kt*64 + slogc[c];
        gl_lds16(sa, (void*)&lds[buf][0][seg * 8]);
        gl_lds16(sb, (void*)&lds[buf][1][seg * 8]);
    };

    // prologue: stage tile 0 fully into buf 0 (8 loads/thread)
    #pragma unroll
    for (int c = 0; c < 4; c++) stage(0, 0, c);

    for (int tk = 0; tk < NT; ++tk){
        const int cur = tk & 1;
        const bool more = (tk + 1) < NT;
        const unsigned short* bufA = &lds[cur][0][0];
        const unsigned short* bufB = &lds[cur][1][0];

        // phase 0: issue next-tile chunk 0, counted wait on prev tile, barrier
        if (more){
            stage(cur ^ 1, tk + 1, 0);
            asm volatile("s_waitcnt vmcnt(2)" ::: "memory");
        } else {
            asm volatile("s_waitcnt vmcnt(0)" ::: "memory");
        }
        __builtin_amdgcn_s_barrier();
        __builtin_amdgcn_sched_barrier(0);
        gphase<0>(bufA, bufB, acc, wm, wn, lr, lg, sl0, sl1);
        __builtin_amdgcn_s_barrier();
        if (more) stage(cur ^ 1, tk + 1, 1);
        gphase<1>(bufA, bufB, acc, wm, wn, lr, lg, sl0, sl1);
        __builtin_amdgcn_s_barrier();
        if (more) stage(cur ^ 1, tk + 1, 2);
        gphase<2>(bufA, bufB, acc, wm, wn, lr, lg, sl0, sl1);
        __builtin_amdgcn_s_barrier();
        if (more) stage(cur ^ 1, tk + 1, 3);
        gphase<3>(bufA, bufB, acc, wm, wn, lr, lg, sl0, sl1);
        __builtin_amdgcn_s_barrier();   // all reads of buf[cur] done before next overwrite
    }

    float bcol[4];
    #pragma unroll
    for (int ni = 0; ni < 4; ni++) bcol[ni] = bias[col0 + wn*64 + ni*16 + lr];
    unsigned short* outp = (unsigned short*)outv;
    #pragma unroll
    for (int mi = 0; mi < 8; mi++){
        #pragma unroll
        for (int j = 0; j < 4; j++){
            size_t row = row0 + wm*128 + mi*16 + lg*4 + j;
            size_t base = row * N + col0 + wn*64 + lr;
            #pragma unroll
            for (int ni = 0; ni < 4; ni++){
                float v = acc[mi][ni][j] + bcol[ni];
                size_t idx = base + (size_t)ni * 16;
                if (EPI == 0) outp[idx] = f2bf(v);
                else          outp[idx] = f2bf(gelu_tanh(v));
            }
        }
    }
}

// ---------------- V pre-transpose: qkv [tok][3C] -> vTg [bh][kt][64 d][80]
__global__ __launch_bounds__(256)
void vtrans(const unsigned short* __restrict__ qkv, unsigned short* __restrict__ vTg){
    __shared__ unsigned short lt[64][68];
    int kt = blockIdx.x & (NQT - 1);
    int bh = blockIdx.x >> 5;
    int h = bh & (TH - 1), b = bh >> 4;
    int t = threadIdx.x;
    int r = t >> 2, c4 = t & 3;
    const unsigned short* src = qkv + (size_t)(b*TT + kt*64 + r) * (3*TC) + 2*TC + h*THD;
    u16x8 a0 = *(const u16x8*)(src + c4*8);
    u16x8 a1 = *(const u16x8*)(src + 32 + c4*8);
    #pragma unroll
    for (int j = 0; j < 8; j++){
        lt[r][c4*8 + j]      = a0[j];
        lt[r][32 + c4*8 + j] = a1[j];
    }
    __syncthreads();
    int d = t >> 2;
    unsigned short* dst = vTg + ((size_t)bh * NQT + kt) * (64*80) + (size_t)d * 80;
    u16x8 o0, o1;
    #pragma unroll
    for (int j = 0; j < 8; j++){
        o0[j] = lt[c4*8 + j][d];
        o1[j] = lt[32 + c4*8 + j][d];
    }
    *(u16x8*)(dst + c4*8)      = o0;
    *(u16x8*)(dst + 32 + c4*8) = o1;
}

// ---------------- flash attention (causal), paired q-tiles, barrier-free
__global__ __launch_bounds__(256, 2)
void attn_kernel(const unsigned short* __restrict__ qkv,
                 const unsigned short* __restrict__ vTg,
                 unsigned short* __restrict__ attn_out){
    __shared__ unsigned short pl[4][2][16*88];  // per-wave P tiles (A,B) — no barriers

    const int bid = blockIdx.x;
    const int pair = bid & 15;           // NQT/2 = 16 pairs
    const int bh = bid >> 4;
    const int h = bh & (TH - 1), b = bh >> 4;
    const int qA = pair, qB = NQT - 1 - pair;
    const int t = threadIdx.x, w = t >> 6, l = t & 63, lr = l & 15, lg = l >> 4;
    const float SC = 0.18033688011112042f;  // 0.125 * log2(e)

    const unsigned short* qbase = qkv + (size_t)(b*TT) * (3*TC) + h*THD;
    const unsigned short* kbase = qkv + (size_t)(b*TT) * (3*TC) + TC + h*THD;
    const unsigned short* vtb = vTg + (size_t)bh * (NQT * 64 * 80);

    const unsigned short* qra = qbase + (size_t)(qA*64 + w*16 + lr) * (3*TC);
    const unsigned short* qrb = qbase + (size_t)(qB*64 + w*16 + lr) * (3*TC);
    bf16x8 qA0 = ldbf8(qra + lg*8), qA1 = ldbf8(qra + 32 + lg*8);
    bf16x8 qB0 = ldbf8(qrb + lg*8), qB1 = ldbf8(qrb + 32 + lg*8);

    bf16x8 ones;
    #pragma unroll
    for (int i = 0; i < 8; i++) ones[i] = (__bf16)1.0f;

    f32x4 oA[5], oB[5];
    float mA[4], mB[4];
    #pragma unroll
    for (int i = 0; i < 5; i++){
        oA[i] = (f32x4){0.f,0.f,0.f,0.f};
        oB[i] = (f32x4){0.f,0.f,0.f,0.f};
    }
    #pragma unroll
    for (int i = 0; i < 4; i++){ mA[i] = -1e30f; mB[i] = -1e30f; }

    auto process_tile = [&](f32x4* s, float* m, f32x4* o, unsigned short* plw){
        float mloc[4];
        #pragma unroll
        for (int j = 0; j < 4; j++)
            mloc[j] = fmaxf(fmaxf(s[0][j], s[1][j]), fmaxf(s[2][j], s[3][j]));
        #pragma unroll
        for (int off = 1; off < 16; off <<= 1)
            #pragma unroll
            for (int j = 0; j < 4; j++)
                mloc[j] = fmaxf(mloc[j], __shfl_xor(mloc[j], off));
        float al[4];
        #pragma unroll
        for (int j = 0; j < 4; j++){
            float mn = fmaxf(m[j], mloc[j]);
            al[j] = exp2f(m[j] - mn);
            m[j] = mn;
        }
        #pragma unroll
        for (int cb = 0; cb < 4; cb++)
            #pragma unroll
            for (int j = 0; j < 4; j++){
                float e = exp2f(s[cb][j] - m[j]);
                ((__bf16*)plw)[(lg*4 + j)*88 + cb*16 + lr] = (__bf16)e;
            }
        #pragma unroll
        for (int db = 0; db < 5; db++)
            #pragma unroll
            for (int j = 0; j < 4; j++) o[db][j] *= al[j];
    };

    auto pv = [&](const bf16x8* v0, const bf16x8* v1, const unsigned short* plw,
                  f32x4* o){
        bf16x8 pa0 = ldbf8(plw + lr*88 + lg*8);
        bf16x8 pa1 = ldbf8(plw + lr*88 + 32 + lg*8);
        #pragma unroll
        for (int db = 0; db < 4; db++){
            o[db] = __builtin_amdgcn_mfma_f32_16x16x32_bf16(pa0, v0[db], o[db], 0,0,0);
            o[db] = __builtin_amdgcn_mfma_f32_16x16x32_bf16(pa1, v1[db], o[db], 0,0,0);
        }
        o[4] = __builtin_amdgcn_mfma_f32_16x16x32_bf16(pa0, ones, o[4], 0,0,0);
        o[4] = __builtin_amdgcn_mfma_f32_16x16x32_bf16(pa1, ones, o[4], 0,0,0);
    };

    for (int kt = 0; kt <= qB; ++kt){
        const bool doA = (kt <= qA);
        const unsigned short* vt = vtb + (size_t)kt * (64*80);
        bf16x8 vf0[4], vf1[4];
        #pragma unroll
        for (int db = 0; db < 4; db++){
            vf0[db] = ldbf8(vt + (db*16 + lr)*80 + lg*8);
            vf1[db] = ldbf8(vt + (db*16 + lr)*80 + 32 + lg*8);
        }
        f32x4 sA[4], sB[4];
        #pragma unroll
        for (int cb = 0; cb < 4; cb++){
            const unsigned short* kb = kbase + (size_t)(kt*64 + cb*16 + lr) * (3*TC);
            bf16x8 k0 = ldbf8(kb + lg*8), k1 = ldbf8(kb + 32 + lg*8);
            f32x4 z = (f32x4){0.f,0.f,0.f,0.f};
            z = __builtin_amdgcn_mfma_f32_16x16x32_bf16(qB0, k0, z, 0,0,0);
            z = __builtin_amdgcn_mfma_f32_16x16x32_bf16(qB1, k1, z, 0,0,0);
            sB[cb] = z;
            if (doA){
                f32x4 za = (f32x4){0.f,0.f,0.f,0.f};
                za = __builtin_amdgcn_mfma_f32_16x16x32_bf16(qA0, k0, za, 0,0,0);
                za = __builtin_amdgcn_mfma_f32_16x16x32_bf16(qA1, k1, za, 0,0,0);
                sA[cb] = za;
            }
        }
        #pragma unroll
        for (int cb = 0; cb < 4; cb++)
            #pragma unroll
            for (int j = 0; j < 4; j++){
                float vb2 = sB[cb][j] * SC;
                if (kt == qB && (cb*16 + lr) > (w*16 + lg*4 + j)) vb2 = -1e30f;
                sB[cb][j] = vb2;
            }
        process_tile(sB, mB, oB, &pl[w][1][0]);
        pv(vf0, vf1, &pl[w][1][0], oB);
        if (doA){
            #pragma unroll
            for (int cb = 0; cb < 4; cb++)
                #pragma unroll
                for (int j = 0; j < 4; j++){
                    float va = sA[cb][j] * SC;
                    if (kt == qA && (cb*16 + lr) > (w*16 + lg*4 + j)) va = -1e30f;
                    sA[cb][j] = va;
                }
            process_tile(sA, mA, oA, &pl[w][0][0]);
            pv(vf0, vf1, &pl[w][0][0], oA);
        }
    }

    __bf16* aout = (__bf16*)attn_out;
    #pragma unroll
    for (int j = 0; j < 4; j++){
        float invB = 1.f / oB[4][j];
        float invA = 1.f / oA[4][j];
        size_t tokB = (size_t)(b*TT + qB*64 + w*16 + lg*4 + j);
        size_t tokA = (size_t)(b*TT + qA*64 + w*16 + lg*4 + j);
        #pragma unroll
        for (int db = 0; db < 4; db++){
            aout[tokB*TC + h*THD + db*16 + lr] = (__bf16)(oB[db][j] * invB);
            aout[tokA*TC + h*THD + db*16 + lr] = (__bf16)(oA[db][j] * invA);
        }
    }
}

extern "C" void kernel_launch(void* const* d_in, const int* in_sizes, int n_in,
                              void* d_out, int out_size, void* d_ws, size_t ws_size,
                              hipStream_t stream){
    const float* x      = (const float*)d_in[0];
    const float* ln1_g  = (const float*)d_in[1];
    const float* ln1_b  = (const float*)d_in[2];
    const float* w_attn = (const float*)d_in[3];
    const float* b_attn = (const float*)d_in[4];
    const float* w_proj = (const float*)d_in[5];
    const float* b_proj = (const float*)d_in[6];
    const float* ln2_g  = (const float*)d_in[7];
    const float* ln2_b  = (const float*)d_in[8];
    const float* w_fc   = (const float*)d_in[9];
    const float* b_fc   = (const float*)d_in[10];
    const float* w_fc2  = (const float*)d_in[11];
    const float* b_fc2  = (const float*)d_in[12];
    float* out = (float*)d_out;

    char* ws = (char*)d_ws;
    size_t off = 0;
    auto alloc = [&](size_t bytes) -> void* {
        void* p = ws + off;
        off += (bytes + 255) & ~(size_t)255;
        return p;
    };
    unsigned short* wattnT = (unsigned short*)alloc((size_t)3072*1024*2);
    unsigned short* wprojT = (unsigned short*)alloc((size_t)1024*1024*2);
    unsigned short* wfcT   = (unsigned short*)alloc((size_t)4096*1024*2);
    unsigned short* wfc2T  = (unsigned short*)alloc((size_t)1024*4096*2);
    unsigned short* xn1    = (unsigned short*)alloc((size_t)TM*TC*2);
    unsigned short* qkvb   = (unsigned short*)alloc((size_t)TM*3*TC*2);
    unsigned short* attnO  = (unsigned short*)alloc((size_t)TM*TC*2);
    float*          resid1 = (float*)alloc((size_t)TM*TC*4);
    unsigned short* xn2    = (unsigned short*)alloc((size_t)TM*TC*2);
    unsigned short* hbuf   = (unsigned short*)alloc((size_t)TM*4*TC*2);
    unsigned short* vTg    = (unsigned short*)alloc((size_t)TB*TH*NQT*64*80*2);

    dim3 tb(32, 8, 1);
    convert_transpose<<<dim3(3072/32, 1024/32), tb, 0, stream>>>(w_attn, wattnT, 1024, 3072);
    convert_transpose<<<dim3(1024/32, 1024/32), tb, 0, stream>>>(w_proj, wprojT, 1024, 1024);
    convert_transpose<<<dim3(4096/32, 1024/32), tb, 0, stream>>>(w_fc,   wfcT,   1024, 4096);
    convert_transpose<<<dim3(1024/32, 4096/32), tb, 0, stream>>>(w_fc2,  wfc2T,  4096, 1024);

    ln_kernel<<<TM, 256, 0, stream>>>(x, ln1_g, ln1_b, xn1);

    gemm256<0><<<(TM/256)*(3072/256), 512, 0, stream>>>(
        xn1, wattnT, b_attn, qkvb, TM, 3072, 1024);

    vtrans<<<TB*TH*NQT, 256, 0, stream>>>(qkvb, vTg);

    attn_kernel<<<TB*TH*(NQT/2), 256, 0, stream>>>(qkvb, vTg, attnO);

    gemm_bt<1><<<(TM/128)*(1024/128), 256, 0, stream>>>(
        attnO, wprojT, b_proj, x, resid1, TM, 1024, 1024);

    ln_kernel<<<TM, 256, 0, stream>>>(resid1, ln2_g, ln2_b, xn2);

    gemm256<2><<<(TM/256)*(4096/256), 512, 0, stream>>>(
        xn2, wfcT, b_fc, hbuf, TM, 4096, 1024);

    gemm_bt<1><<<(TM/128)*(1024/128), 256, 0, stream>>>(
        hbuf, wfc2T, b_fc2, resid1, out, TM, 1024, 4096);
}